// Round 13
// baseline (294.565 us; speedup 1.0000x reference)
//
#include <hip/hip_runtime.h>
#include <hip/hip_bf16.h>
#include <math.h>

#define NN 100000      // nodes
#define NE 1600000     // edges
#define HD 64          // feature dim
#define NG 1000        // graphs
#define NC 10          // classes

#define NB 782         // buckets = ceil(NN/128), bucket = dst>>7 (128-node range)
#define NBLK 196       // partition blocks (R10-proven geometry)
#define EPB 8164       // edges per partition block = ceil(NE/NBLK)
#define GBB 391        // graph_bounds blocks = ceil(NN/256)

typedef __attribute__((ext_vector_type(8))) short bf16x8;
typedef __attribute__((ext_vector_type(4))) float f32x4;

__device__ __forceinline__ unsigned short f32_to_bf16(float f) {
    union { float f; unsigned u; } c; c.f = f;
    unsigned u = c.u;
    u += 0x7FFFu + ((u >> 16) & 1u);   // round-to-nearest-even
    return (unsigned short)(u >> 16);
}
#define BFLO(u) __uint_as_float((u) << 16)
#define BFHI(u) __uint_as_float((u) & 0xFFFF0000u)

// ---------------- P1: per-block bucket histogram (+ fused per-bucket totals) ----------------
__global__ __launch_bounds__(256) void hist_buckets(const int* __restrict__ dst,
                                                    int* __restrict__ hist,
                                                    int* __restrict__ btotal)
{
    __shared__ int cnt[NB];
    int t = threadIdx.x, blk = blockIdx.x;
    for (int i = t; i < NB; i += 256) cnt[i] = 0;
    __syncthreads();
    int e0 = blk * EPB;
    int e1 = e0 + EPB; if (e1 > NE) e1 = NE;
    for (int e = e0 + t; e < e1; e += 256) atomicAdd(&cnt[dst[e] >> 7], 1);
    __syncthreads();
    for (int i = t; i < NB; i += 256) {
        int c = cnt[i];
        hist[(size_t)i * NBLK + blk] = c;
        if (c) atomicAdd(&btotal[i], c);     // fused bucket_total (btotal pre-zeroed)
    }
}

// ---------------- P2a: scan bucket totals -> bucketoff (one block, LDS only) ----------------
__global__ __launch_bounds__(1024) void scan_totals(const int* __restrict__ btotal,
                                                    int* __restrict__ bucketoff)
{
    __shared__ int sm[1024];
    int t = threadIdx.x;
    int v = (t < NB) ? btotal[t] : 0;
    sm[t] = v;
    __syncthreads();
    for (int off = 1; off < 1024; off <<= 1) {
        int u = (t >= off) ? sm[t - off] : 0;
        __syncthreads();
        sm[t] += u;
        __syncthreads();
    }
    if (t <= NB) bucketoff[t] = sm[t] - ((t < NB) ? v : 0);
}

// ---------------- P2b: hist counts -> absolute write offsets (wave per bucket) ----------------
__global__ __launch_bounds__(256) void scan_hist(int* __restrict__ hist,
                                                 const int* __restrict__ bucketoff)
{
    int w = (blockIdx.x * 256 + threadIdx.x) >> 6;
    int lane = threadIdx.x & 63;
    if (w >= NB) return;
    int run = bucketoff[w];
    int* row = hist + (size_t)w * NBLK;
    for (int c0 = 0; c0 < NBLK; c0 += 64) {
        int idx = c0 + lane;
        int v = (idx < NBLK) ? row[idx] : 0;
        int incl = v;
#pragma unroll
        for (int off = 1; off < 64; off <<= 1) {
            int u = __shfl_up(incl, off);
            if (lane >= off) incl += u;
        }
        if (idx < NBLK) row[idx] = run + incl - v;
        run += __shfl(incl, 63);
    }
}

// ---------------- P3: bin edges -> packed pairs  (+ graph_bounds piggybacked) ----------------
__global__ __launch_bounds__(256) void bin_and_bounds(const int* __restrict__ src,
                                                      const int* __restrict__ dst,
                                                      const int* __restrict__ hist,
                                                      unsigned* __restrict__ pairs,
                                                      const int* __restrict__ batch,
                                                      int* __restrict__ gstart)
{
    int blk = blockIdx.x;
    if (blk >= NBLK) {                       // graph-bounds part
        int i = (blk - NBLK) * 256 + threadIdx.x;
        if (i >= NN) return;
        int b = batch[i];
        if (i == 0) {
            for (int g = 0; g <= b; ++g) gstart[g] = 0;
        } else {
            int p = batch[i - 1];
            for (int g = p + 1; g <= b; ++g) gstart[g] = i;
        }
        if (i == NN - 1) {
            for (int g = b + 1; g <= NG; ++g) gstart[g] = NN;
        }
        return;
    }
    __shared__ int cur[NB];
    int t = threadIdx.x;
    for (int i = t; i < NB; i += 256) cur[i] = hist[(size_t)i * NBLK + blk];
    __syncthreads();
    int e0 = blk * EPB;
    int e1 = e0 + EPB; if (e1 > NE) e1 = NE;
    for (int e = e0 + t; e < e1; e += 256) {
        int d = dst[e], s = src[e];
        int b = d >> 7;
        int pos = atomicAdd(&cur[b], 1);
        pairs[pos] = ((unsigned)(d & 127) << 17) | (unsigned)s;
    }
}

// ---------------- P4: per-bucket counting sort -> srcidx (dst-sorted), rowstart, dinv ----------------
__global__ __launch_bounds__(256) void sort_bucket(const int* __restrict__ bucketoff,
                                                   const unsigned* __restrict__ pairs,
                                                   int* __restrict__ rowstart,
                                                   int* __restrict__ srcidx,
                                                   float* __restrict__ dinv)
{
    __shared__ int cnt[128], off[128], cur[128];
    int b = blockIdx.x, t = threadIdx.x;
    int e0 = bucketoff[b], e1 = bucketoff[b + 1];
    if (t < 128) cnt[t] = 0;
    __syncthreads();
    for (int e = e0 + t; e < e1; e += 256) atomicAdd(&cnt[pairs[e] >> 17], 1);
    __syncthreads();
    if (t < 128) off[t] = cnt[t];
    __syncthreads();
    for (int o = 1; o < 128; o <<= 1) {           // Hillis-Steele inclusive scan
        int u = (t < 128 && t >= o) ? off[t - o] : 0;
        __syncthreads();
        if (t < 128) off[t] += u;
        __syncthreads();
    }
    if (t < 128) {
        int ex = e0 + off[t] - cnt[t];            // exclusive + bucket base
        cur[t] = ex;
        int node = (b << 7) + t;
        if (node < NN) {
            rowstart[node] = ex;
            dinv[node] = rsqrtf((float)cnt[t] + 1.0f);
        }
    }
    if (b == NB - 1 && t == 0) rowstart[NN] = e1; // == NE
    __syncthreads();
    for (int e = e0 + t; e < e1; e += 256) {
        unsigned pk = pairs[e];
        int pos = atomicAdd(&cur[pk >> 17], 1);
        srcidx[pos] = (int)(pk & 0x1FFFF);        // block-local contiguous region
    }
}

// ---------------- per-layer GEMM via MFMA: y = bf16((h @ W^T) * dinv) ----------------
// mfma_f32_16x16x32_bf16. A: lane l -> h[m0+(l&15)][ (l>>4)*8+j ]; B: lane l ->
// W[c*16+(l&15)][ kb*32+(l>>4)*8+j ]; D: col=l&15, row=(l>>4)*4+reg (m89-verified).
__global__ __launch_bounds__(256) void gemm_mfma(const float* __restrict__ h,
                                                 const float* __restrict__ W,
                                                 const float* __restrict__ dinv,
                                                 unsigned short* __restrict__ y,
                                                 int nrows)
{
    const int t = threadIdx.x;
    const int lane = t & 63;
    const int wave = t >> 6;
    const int rbase = blockIdx.x * 64;
    const int l15 = lane & 15;
    const int kq  = lane >> 4;               // 0..3

    bf16x8 Bf[4][2];
#pragma unroll
    for (int c = 0; c < 4; ++c) {
#pragma unroll
        for (int kb = 0; kb < 2; ++kb) {
            const float* wp = W + (c * 16 + l15) * 64 + kb * 32 + kq * 8;
            float f[8];
            *(float4*)(f)     = *(const float4*)(wp);
            *(float4*)(f + 4) = *(const float4*)(wp + 4);
            bf16x8 v;
#pragma unroll
            for (int i = 0; i < 8; ++i) v[i] = (short)f32_to_bf16(f[i]);
            Bf[c][kb] = v;
        }
    }

    int arow = rbase + wave * 16 + l15;
    if (arow >= nrows) arow = nrows - 1;
    bf16x8 Af[2];
#pragma unroll
    for (int kb = 0; kb < 2; ++kb) {
        const float* hp = h + (size_t)arow * 64 + kb * 32 + kq * 8;
        float f[8];
        *(float4*)(f)     = *(const float4*)(hp);
        *(float4*)(f + 4) = *(const float4*)(hp + 4);
        bf16x8 v;
#pragma unroll
        for (int i = 0; i < 8; ++i) v[i] = (short)f32_to_bf16(f[i]);
        Af[kb] = v;
    }

    f32x4 acc[4] = {{0.f,0.f,0.f,0.f},{0.f,0.f,0.f,0.f},{0.f,0.f,0.f,0.f},{0.f,0.f,0.f,0.f}};
#pragma unroll
    for (int c = 0; c < 4; ++c) {
        acc[c] = __builtin_amdgcn_mfma_f32_16x16x32_bf16(Af[0], Bf[c][0], acc[c], 0, 0, 0);
        acc[c] = __builtin_amdgcn_mfma_f32_16x16x32_bf16(Af[1], Bf[c][1], acc[c], 0, 0, 0);
    }

    const int drow0 = rbase + wave * 16 + kq * 4;
#pragma unroll
    for (int r = 0; r < 4; ++r) {
        int rg = drow0 + r;
        if (rg < nrows) {
            float d = dinv[rg];
#pragma unroll
            for (int c = 0; c < 4; ++c)
                y[(size_t)rg * 64 + c * 16 + l15] = f32_to_bf16(acc[c][r] * d);
        }
    }
}

// ---------------- pull aggregation: one node per HALF-WAVE (32 lanes = full 128B row) ----------------
#define NPN 2   // nodes per half-wave (sequential)
__global__ __launch_bounds__(256) void pull_aggr(const int* __restrict__ rowstart,
                                                 const int* __restrict__ srcidx,
                                                 const unsigned* __restrict__ y,   // 32 u32 per row
                                                 const float* __restrict__ dinv,
                                                 const float* __restrict__ bias,
                                                 float* __restrict__ hout)
{
    int hw = (blockIdx.x * blockDim.x + threadIdx.x) >> 5;   // global half-wave id
    int fl = threadIdx.x & 31;
    int hb = threadIdx.x & 32;       // base lane of this half within the 64-lane wave
    float2 bb = ((const float2*)bias)[fl];

#pragma unroll 1
    for (int i = 0; i < NPN; ++i) {
        int n = hw * NPN + i;
        if (n >= NN) return;
        int s0 = rowstart[n], s1 = rowstart[n + 1];
        unsigned su = y[(size_t)n * 32 + fl];          // self-loop term
        float acc0 = BFLO(su), acc1 = BFHI(su);
        for (int base = s0; base < s1; base += 32) {
            int nb = s1 - base; if (nb > 32) nb = 32;
            int idx = (fl < nb) ? srcidx[base + fl] : 0;   // 128B coalesced batch per half
            int j = 0;
            for (; j + 8 <= nb; j += 8) {              // 8 row-gathers in flight per half-wave
                int e0 = __shfl(idx, hb + j + 0), e1 = __shfl(idx, hb + j + 1);
                int e2 = __shfl(idx, hb + j + 2), e3 = __shfl(idx, hb + j + 3);
                int e4 = __shfl(idx, hb + j + 4), e5 = __shfl(idx, hb + j + 5);
                int e6 = __shfl(idx, hb + j + 6), e7 = __shfl(idx, hb + j + 7);
                unsigned u0 = y[(size_t)e0 * 32 + fl];
                unsigned u1 = y[(size_t)e1 * 32 + fl];
                unsigned u2 = y[(size_t)e2 * 32 + fl];
                unsigned u3 = y[(size_t)e3 * 32 + fl];
                unsigned u4 = y[(size_t)e4 * 32 + fl];
                unsigned u5 = y[(size_t)e5 * 32 + fl];
                unsigned u6 = y[(size_t)e6 * 32 + fl];
                unsigned u7 = y[(size_t)e7 * 32 + fl];
                acc0 += BFLO(u0); acc1 += BFHI(u0);
                acc0 += BFLO(u1); acc1 += BFHI(u1);
                acc0 += BFLO(u2); acc1 += BFHI(u2);
                acc0 += BFLO(u3); acc1 += BFHI(u3);
                acc0 += BFLO(u4); acc1 += BFHI(u4);
                acc0 += BFLO(u5); acc1 += BFHI(u5);
                acc0 += BFLO(u6); acc1 += BFHI(u6);
                acc0 += BFLO(u7); acc1 += BFHI(u7);
            }
            for (; j < nb; ++j) {
                int e = __shfl(idx, hb + j);
                unsigned u = y[(size_t)e * 32 + fl];
                acc0 += BFLO(u); acc1 += BFHI(u);
            }
        }
        float d = dinv[n];
        float2 v;
        v.x = fmaxf(fmaf(acc0, d, bb.x), 0.f);
        v.y = fmaxf(fmaf(acc1, d, bb.y), 0.f);
        ((float2*)hout)[(size_t)n * 32 + fl] = v;      // 256B contiguous per half-wave
    }
}

// ---------------- pool (mean per graph, precomputed bounds) + FFN + softmax ----------------
__global__ __launch_bounds__(256) void pool_ffn(const float* __restrict__ h3,
                                                const int* __restrict__ gstart,
                                                const float* __restrict__ Wf,
                                                const float* __restrict__ bf,
                                                float* __restrict__ pooled,
                                                float* __restrict__ ffn,
                                                float* __restrict__ soft)
{
    __shared__ float part[4][64];
    int g = blockIdx.x;
    int t = threadIdx.x, wv = t >> 6, lane = t & 63;
    int start = gstart[g], end = gstart[g + 1];

    float acc = 0.f;
    for (int n = start + wv; n < end; n += 4) acc += h3[(size_t)n * 64 + lane];
    part[wv][lane] = acc;
    __syncthreads();
    if (wv != 0) return;

    float a = part[0][lane] + part[1][lane] + part[2][lane] + part[3][lane];
    float cnt = (float)(end - start);
    float pv = a / fmaxf(cnt, 1.0f);
    pooled[g * 64 + lane] = pv;

    float f = 0.f;
#pragma unroll
    for (int cls = 0; cls < NC; ++cls) {
        float v = pv * Wf[cls * 64 + lane];
#pragma unroll
        for (int off = 32; off; off >>= 1) v += __shfl_xor(v, off);
        if (lane == cls) f = v;
    }
    float fb = (lane < NC) ? fmaxf(f + bf[lane], 0.f) : -INFINITY;
    if (lane < NC) ffn[g * NC + lane] = fb;

    float m = fb;
#pragma unroll
    for (int off = 32; off; off >>= 1) m = fmaxf(m, __shfl_xor(m, off));
    float e = (lane < NC) ? expf(fb - m) : 0.f;
    float s = e;
#pragma unroll
    for (int off = 32; off; off >>= 1) s += __shfl_xor(s, off);
    if (lane < NC) soft[g * NC + lane] = e / s;
}

extern "C" void kernel_launch(void* const* d_in, const int* in_sizes, int n_in,
                              void* d_out, int out_size, void* d_ws, size_t ws_size,
                              hipStream_t stream) {
    const float* x   = (const float*)d_in[0];
    const int*   ei  = (const int*)d_in[1];
    const int*   bat = (const int*)d_in[2];
    const float* W1  = (const float*)d_in[3];
    const float* b1  = (const float*)d_in[4];
    const float* W2  = (const float*)d_in[5];
    const float* b2  = (const float*)d_in[6];
    const float* W3  = (const float*)d_in[7];
    const float* b3  = (const float*)d_in[8];
    const float* Wf  = (const float*)d_in[9];
    const float* bf  = (const float*)d_in[10];

    const int* src = ei;
    const int* dst = ei + NE;

    float* out    = (float*)d_out;
    float* h1     = out;
    float* h2     = out + (size_t)NN * HD;
    float* h3     = out + (size_t)2 * NN * HD;
    float* pooled = out + (size_t)3 * NN * HD;
    float* ffn    = pooled + (size_t)NG * HD;
    float* soft   = ffn + (size_t)NG * NC;

    // workspace layout (bytes):
    //   dinv      [NN f32]        @ 0
    //   rowstart  [NN+1 i32]      @ 400000
    //   srcidx    [NE i32]        @ 800016          (ends 7,200,016)
    //   y         [NN*64 bf16]    @ 7200016         (ends 20,000,016)
    //   gstart    [NG+1 i32]      @ 20000016
    //   -- partition temporaries overlap y (dead before first gemm writes y):
    //   pairs     [NE u32]        @ 7200016
    //   hist      [NB*NBLK i32]   @ 13600016        (782*196*4 = 613,088 B)
    //   bucketoff [NB+1 i32]      @ 14213504
    //   btotal    [NB i32]        @ 14216640
    char* ws = (char*)d_ws;
    float*          dinv      = (float*)(ws + 0);
    int*            rowstart  = (int*)(ws + 400000);
    int*            srcidx    = (int*)(ws + 800016);
    unsigned short* y         = (unsigned short*)(ws + 7200016);
    int*            gstart    = (int*)(ws + 20000016);
    unsigned*       pairs     = (unsigned*)(ws + 7200016);
    int*            hist      = (int*)(ws + 13600016);
    int*            bucketoff = (int*)(ws + 14213504);
    int*            btotal    = (int*)(ws + 14216640);

    // ---- edge partition + per-bucket counting sort (amortized across 3 layers) ----
    hipMemsetAsync(btotal, 0, NB * sizeof(int), stream);
    hist_buckets<<<NBLK, 256, 0, stream>>>(dst, hist, btotal);
    scan_totals<<<1, 1024, 0, stream>>>(btotal, bucketoff);
    scan_hist<<<(NB + 3) / 4, 256, 0, stream>>>(hist, bucketoff);
    bin_and_bounds<<<NBLK + GBB, 256, 0, stream>>>(src, dst, hist, pairs, bat, gstart);
    sort_bucket<<<NB, 256, 0, stream>>>(bucketoff, pairs, rowstart, srcidx, dinv);

    const int gemmGrid = (NN + 63) / 64;
    const int aggrGrid = (NN + 8 * NPN - 1) / (8 * NPN);   // 8 half-waves/block, NPN nodes each

    gemm_mfma<<<gemmGrid, 256, 0, stream>>>(x, W1, dinv, y, NN);
    pull_aggr<<<aggrGrid, 256, 0, stream>>>(rowstart, srcidx, (const unsigned*)y, dinv, b1, h1);

    gemm_mfma<<<gemmGrid, 256, 0, stream>>>(h1, W2, dinv, y, NN);
    pull_aggr<<<aggrGrid, 256, 0, stream>>>(rowstart, srcidx, (const unsigned*)y, dinv, b2, h2);

    gemm_mfma<<<gemmGrid, 256, 0, stream>>>(h2, W3, dinv, y, NN);
    pull_aggr<<<aggrGrid, 256, 0, stream>>>(rowstart, srcidx, (const unsigned*)y, dinv, b3, h3);

    pool_ffn<<<NG, 256, 0, stream>>>(h3, gstart, Wf, bf, pooled, ffn, soft);
}

// Round 14
// 286.092 us; speedup vs baseline: 1.0296x; 1.0296x over previous
//
#include <hip/hip_runtime.h>
#include <hip/hip_bf16.h>
#include <math.h>

#define NN 100000      // nodes
#define NE 1600000     // edges
#define HD 64          // feature dim
#define NG 1000        // graphs
#define NC 10          // classes

#define NB 782         // buckets = ceil(NN/128), bucket = dst>>7 (128-node range)
#define NBLK 196       // partition blocks
#define EPB 8164       // edges per partition block = ceil(NE/NBLK)

typedef __attribute__((ext_vector_type(8))) short bf16x8;
typedef __attribute__((ext_vector_type(4))) float f32x4;

__device__ __forceinline__ unsigned short f32_to_bf16(float f) {
    union { float f; unsigned u; } c; c.f = f;
    unsigned u = c.u;
    u += 0x7FFFu + ((u >> 16) & 1u);   // round-to-nearest-even
    return (unsigned short)(u >> 16);
}
#define BFLO(u) __uint_as_float((u) << 16)
#define BFHI(u) __uint_as_float((u) & 0xFFFF0000u)

// ---------------- pass 1a: per-block bucket histogram ----------------
__global__ __launch_bounds__(256) void hist_buckets(const int* __restrict__ dst,
                                                    int* __restrict__ hist)
{
    __shared__ int cnt[NB];
    int t = threadIdx.x, blk = blockIdx.x;
    for (int i = t; i < NB; i += 256) cnt[i] = 0;
    __syncthreads();
    int e0 = blk * EPB;
    int e1 = e0 + EPB; if (e1 > NE) e1 = NE;
    for (int e = e0 + t; e < e1; e += 256) atomicAdd(&cnt[dst[e] >> 7], 1);
    __syncthreads();
    for (int i = t; i < NB; i += 256) hist[(size_t)i * NBLK + blk] = cnt[i];
}

// ---------------- pass 1b: per-bucket totals ----------------
__global__ __launch_bounds__(256) void bucket_total(const int* __restrict__ hist,
                                                    int* __restrict__ btotal)
{
    int w = (blockIdx.x * 256 + threadIdx.x) >> 6;
    int lane = threadIdx.x & 63;
    if (w >= NB) return;
    const int* row = hist + (size_t)w * NBLK;
    int s = 0;
    for (int i = lane; i < NBLK; i += 64) s += row[i];
#pragma unroll
    for (int off = 32; off; off >>= 1) s += __shfl_xor(s, off);
    if (lane == 0) btotal[w] = s;
}

// ---------------- pass 1c: scan bucket totals -> bucketoff ----------------
__global__ __launch_bounds__(1024) void scan_totals(const int* __restrict__ btotal,
                                                    int* __restrict__ bucketoff)
{
    __shared__ int sm[1024];
    int t = threadIdx.x;
    int v = (t < NB) ? btotal[t] : 0;
    sm[t] = v;
    __syncthreads();
    for (int off = 1; off < 1024; off <<= 1) {
        int u = (t >= off) ? sm[t - off] : 0;
        __syncthreads();
        sm[t] += u;
        __syncthreads();
    }
    if (t <= NB) bucketoff[t] = sm[t] - ((t < NB) ? v : 0);
}

// ---------------- pass 1d: hist counts -> global write offsets (in place) ----------------
__global__ __launch_bounds__(256) void scan_hist(int* __restrict__ hist,
                                                 const int* __restrict__ bucketoff)
{
    int w = (blockIdx.x * 256 + threadIdx.x) >> 6;
    int lane = threadIdx.x & 63;
    if (w >= NB) return;
    int run = bucketoff[w];
    int* row = hist + (size_t)w * NBLK;
    for (int c0 = 0; c0 < NBLK; c0 += 64) {
        int idx = c0 + lane;
        int v = (idx < NBLK) ? row[idx] : 0;
        int incl = v;
#pragma unroll
        for (int off = 1; off < 64; off <<= 1) {
            int u = __shfl_up(incl, off);
            if (lane >= off) incl += u;
        }
        if (idx < NBLK) row[idx] = run + incl - v;
        run += __shfl(incl, 63);
    }
}

// ---------------- pass 2: bin edges -> packed pairs (row7|src17), grouped by bucket ----------------
__global__ __launch_bounds__(256) void bin_edges(const int* __restrict__ src,
                                                 const int* __restrict__ dst,
                                                 const int* __restrict__ hist,
                                                 unsigned* __restrict__ pairs)
{
    __shared__ int cur[NB];
    int t = threadIdx.x, blk = blockIdx.x;
    for (int i = t; i < NB; i += 256) cur[i] = hist[(size_t)i * NBLK + blk];
    __syncthreads();
    int e0 = blk * EPB;
    int e1 = e0 + EPB; if (e1 > NE) e1 = NE;
    for (int e = e0 + t; e < e1; e += 256) {
        int d = dst[e], s = src[e];
        int b = d >> 7;
        int pos = atomicAdd(&cur[b], 1);
        pairs[pos] = ((unsigned)(d & 127) << 17) | (unsigned)s;
    }
}

// ---------------- pass 3: per-bucket counting sort -> srcidx (dst-sorted), rowstart, dinv ----------------
__global__ __launch_bounds__(256) void sort_bucket(const int* __restrict__ bucketoff,
                                                   const unsigned* __restrict__ pairs,
                                                   int* __restrict__ rowstart,
                                                   int* __restrict__ srcidx,
                                                   float* __restrict__ dinv)
{
    __shared__ int cnt[128], off[128], cur[128];
    int b = blockIdx.x, t = threadIdx.x;
    int e0 = bucketoff[b], e1 = bucketoff[b + 1];
    if (t < 128) cnt[t] = 0;
    __syncthreads();
    for (int e = e0 + t; e < e1; e += 256) atomicAdd(&cnt[pairs[e] >> 17], 1);
    __syncthreads();
    if (t < 128) off[t] = cnt[t];
    __syncthreads();
    for (int o = 1; o < 128; o <<= 1) {           // Hillis-Steele inclusive scan
        int u = (t < 128 && t >= o) ? off[t - o] : 0;
        __syncthreads();
        if (t < 128) off[t] += u;
        __syncthreads();
    }
    if (t < 128) {
        int ex = e0 + off[t] - cnt[t];            // exclusive + bucket base
        cur[t] = ex;
        int node = (b << 7) + t;
        if (node < NN) {
            rowstart[node] = ex;
            dinv[node] = rsqrtf((float)cnt[t] + 1.0f);
        }
    }
    if (b == NB - 1 && t == 0) rowstart[NN] = e1; // == NE
    __syncthreads();
    for (int e = e0 + t; e < e1; e += 256) {
        unsigned pk = pairs[e];
        int pos = atomicAdd(&cur[pk >> 17], 1);
        srcidx[pos] = (int)(pk & 0x1FFFF);        // block-local contiguous region
    }
}

// ---------------- graph boundaries on sorted batch ----------------
__global__ __launch_bounds__(256) void graph_bounds(const int* __restrict__ batch,
                                                    int* __restrict__ gstart)
{
    int i = blockIdx.x * 256 + threadIdx.x;
    if (i >= NN) return;
    int b = batch[i];
    if (i == 0) {
        for (int g = 0; g <= b; ++g) gstart[g] = 0;
    } else {
        int p = batch[i - 1];
        for (int g = p + 1; g <= b; ++g) gstart[g] = i;
    }
    if (i == NN - 1) {
        for (int g = b + 1; g <= NG; ++g) gstart[g] = NN;
    }
}

// ---------------- per-layer GEMM via MFMA: y = bf16((h @ W^T) * dinv) ----------------
// mfma_f32_16x16x32_bf16. A: lane l -> h[m0+(l&15)][ (l>>4)*8+j ]; B: lane l ->
// W[c*16+(l&15)][ kb*32+(l>>4)*8+j ]; D: col=l&15, row=(l>>4)*4+reg (m89-verified).
__global__ __launch_bounds__(256) void gemm_mfma(const float* __restrict__ h,
                                                 const float* __restrict__ W,
                                                 const float* __restrict__ dinv,
                                                 unsigned short* __restrict__ y,
                                                 int nrows)
{
    const int t = threadIdx.x;
    const int lane = t & 63;
    const int wave = t >> 6;
    const int rbase = blockIdx.x * 64;
    const int l15 = lane & 15;
    const int kq  = lane >> 4;               // 0..3

    bf16x8 Bf[4][2];
#pragma unroll
    for (int c = 0; c < 4; ++c) {
#pragma unroll
        for (int kb = 0; kb < 2; ++kb) {
            const float* wp = W + (c * 16 + l15) * 64 + kb * 32 + kq * 8;
            float f[8];
            *(float4*)(f)     = *(const float4*)(wp);
            *(float4*)(f + 4) = *(const float4*)(wp + 4);
            bf16x8 v;
#pragma unroll
            for (int i = 0; i < 8; ++i) v[i] = (short)f32_to_bf16(f[i]);
            Bf[c][kb] = v;
        }
    }

    int arow = rbase + wave * 16 + l15;
    if (arow >= nrows) arow = nrows - 1;
    bf16x8 Af[2];
#pragma unroll
    for (int kb = 0; kb < 2; ++kb) {
        const float* hp = h + (size_t)arow * 64 + kb * 32 + kq * 8;
        float f[8];
        *(float4*)(f)     = *(const float4*)(hp);
        *(float4*)(f + 4) = *(const float4*)(hp + 4);
        bf16x8 v;
#pragma unroll
        for (int i = 0; i < 8; ++i) v[i] = (short)f32_to_bf16(f[i]);
        Af[kb] = v;
    }

    f32x4 acc[4] = {{0.f,0.f,0.f,0.f},{0.f,0.f,0.f,0.f},{0.f,0.f,0.f,0.f},{0.f,0.f,0.f,0.f}};
#pragma unroll
    for (int c = 0; c < 4; ++c) {
        acc[c] = __builtin_amdgcn_mfma_f32_16x16x32_bf16(Af[0], Bf[c][0], acc[c], 0, 0, 0);
        acc[c] = __builtin_amdgcn_mfma_f32_16x16x32_bf16(Af[1], Bf[c][1], acc[c], 0, 0, 0);
    }

    const int drow0 = rbase + wave * 16 + kq * 4;
#pragma unroll
    for (int r = 0; r < 4; ++r) {
        int rg = drow0 + r;
        if (rg < nrows) {
            float d = dinv[rg];
#pragma unroll
            for (int c = 0; c < 4; ++c)
                y[(size_t)rg * 64 + c * 16 + l15] = f32_to_bf16(acc[c][r] * d);
        }
    }
}

// ---------------- pull aggregation: one node per HALF-WAVE (32 lanes = full 128B row) ----------------
#define NPN 2   // nodes per half-wave (sequential)
__global__ __launch_bounds__(256) void pull_aggr(const int* __restrict__ rowstart,
                                                 const int* __restrict__ srcidx,
                                                 const unsigned* __restrict__ y,   // 32 u32 per row
                                                 const float* __restrict__ dinv,
                                                 const float* __restrict__ bias,
                                                 float* __restrict__ hout)
{
    int hw = (blockIdx.x * blockDim.x + threadIdx.x) >> 5;   // global half-wave id
    int fl = threadIdx.x & 31;
    int hb = threadIdx.x & 32;       // base lane of this half within the 64-lane wave
    float2 bb = ((const float2*)bias)[fl];

#pragma unroll 1
    for (int i = 0; i < NPN; ++i) {
        int n = hw * NPN + i;
        if (n >= NN) return;
        int s0 = rowstart[n], s1 = rowstart[n + 1];
        unsigned su = y[(size_t)n * 32 + fl];          // self-loop term
        float acc0 = BFLO(su), acc1 = BFHI(su);
        for (int base = s0; base < s1; base += 32) {
            int nb = s1 - base; if (nb > 32) nb = 32;
            int idx = (fl < nb) ? srcidx[base + fl] : 0;   // 128B coalesced batch per half
            int j = 0;
            for (; j + 8 <= nb; j += 8) {              // 8 row-gathers in flight per half-wave
                int e0 = __shfl(idx, hb + j + 0), e1 = __shfl(idx, hb + j + 1);
                int e2 = __shfl(idx, hb + j + 2), e3 = __shfl(idx, hb + j + 3);
                int e4 = __shfl(idx, hb + j + 4), e5 = __shfl(idx, hb + j + 5);
                int e6 = __shfl(idx, hb + j + 6), e7 = __shfl(idx, hb + j + 7);
                unsigned u0 = y[(size_t)e0 * 32 + fl];
                unsigned u1 = y[(size_t)e1 * 32 + fl];
                unsigned u2 = y[(size_t)e2 * 32 + fl];
                unsigned u3 = y[(size_t)e3 * 32 + fl];
                unsigned u4 = y[(size_t)e4 * 32 + fl];
                unsigned u5 = y[(size_t)e5 * 32 + fl];
                unsigned u6 = y[(size_t)e6 * 32 + fl];
                unsigned u7 = y[(size_t)e7 * 32 + fl];
                acc0 += BFLO(u0); acc1 += BFHI(u0);
                acc0 += BFLO(u1); acc1 += BFHI(u1);
                acc0 += BFLO(u2); acc1 += BFHI(u2);
                acc0 += BFLO(u3); acc1 += BFHI(u3);
                acc0 += BFLO(u4); acc1 += BFHI(u4);
                acc0 += BFLO(u5); acc1 += BFHI(u5);
                acc0 += BFLO(u6); acc1 += BFHI(u6);
                acc0 += BFLO(u7); acc1 += BFHI(u7);
            }
            for (; j < nb; ++j) {
                int e = __shfl(idx, hb + j);
                unsigned u = y[(size_t)e * 32 + fl];
                acc0 += BFLO(u); acc1 += BFHI(u);
            }
        }
        float d = dinv[n];
        float2 v;
        v.x = fmaxf(fmaf(acc0, d, bb.x), 0.f);
        v.y = fmaxf(fmaf(acc1, d, bb.y), 0.f);
        ((float2*)hout)[(size_t)n * 32 + fl] = v;      // 256B contiguous per half-wave
    }
}

// ---------------- pool (mean per graph, precomputed bounds) + FFN + softmax ----------------
__global__ __launch_bounds__(256) void pool_ffn(const float* __restrict__ h3,
                                                const int* __restrict__ gstart,
                                                const float* __restrict__ Wf,
                                                const float* __restrict__ bf,
                                                float* __restrict__ pooled,
                                                float* __restrict__ ffn,
                                                float* __restrict__ soft)
{
    __shared__ float part[4][64];
    int g = blockIdx.x;
    int t = threadIdx.x, wv = t >> 6, lane = t & 63;
    int start = gstart[g], end = gstart[g + 1];

    float acc = 0.f;
    for (int n = start + wv; n < end; n += 4) acc += h3[(size_t)n * 64 + lane];
    part[wv][lane] = acc;
    __syncthreads();
    if (wv != 0) return;

    float a = part[0][lane] + part[1][lane] + part[2][lane] + part[3][lane];
    float cnt = (float)(end - start);
    float pv = a / fmaxf(cnt, 1.0f);
    pooled[g * 64 + lane] = pv;

    float f = 0.f;
#pragma unroll
    for (int cls = 0; cls < NC; ++cls) {
        float v = pv * Wf[cls * 64 + lane];
#pragma unroll
        for (int off = 32; off; off >>= 1) v += __shfl_xor(v, off);
        if (lane == cls) f = v;
    }
    float fb = (lane < NC) ? fmaxf(f + bf[lane], 0.f) : -INFINITY;
    if (lane < NC) ffn[g * NC + lane] = fb;

    float m = fb;
#pragma unroll
    for (int off = 32; off; off >>= 1) m = fmaxf(m, __shfl_xor(m, off));
    float e = (lane < NC) ? expf(fb - m) : 0.f;
    float s = e;
#pragma unroll
    for (int off = 32; off; off >>= 1) s += __shfl_xor(s, off);
    if (lane < NC) soft[g * NC + lane] = e / s;
}

extern "C" void kernel_launch(void* const* d_in, const int* in_sizes, int n_in,
                              void* d_out, int out_size, void* d_ws, size_t ws_size,
                              hipStream_t stream) {
    const float* x   = (const float*)d_in[0];
    const int*   ei  = (const int*)d_in[1];
    const int*   bat = (const int*)d_in[2];
    const float* W1  = (const float*)d_in[3];
    const float* b1  = (const float*)d_in[4];
    const float* W2  = (const float*)d_in[5];
    const float* b2  = (const float*)d_in[6];
    const float* W3  = (const float*)d_in[7];
    const float* b3  = (const float*)d_in[8];
    const float* Wf  = (const float*)d_in[9];
    const float* bf  = (const float*)d_in[10];

    const int* src = ei;
    const int* dst = ei + NE;

    float* out    = (float*)d_out;
    float* h1     = out;
    float* h2     = out + (size_t)NN * HD;
    float* h3     = out + (size_t)2 * NN * HD;
    float* pooled = out + (size_t)3 * NN * HD;
    float* ffn    = pooled + (size_t)NG * HD;
    float* soft   = ffn + (size_t)NG * NC;

    // workspace layout (bytes):
    //   dinv      [NN f32]        @ 0
    //   rowstart  [NN+1 i32]      @ 400000
    //   srcidx    [NE i32]        @ 800016          (ends 7,200,016)
    //   y         [NN*64 bf16]    @ 7200016         (ends 20,000,016)
    //   gstart    [NG+1 i32]      @ 20000016
    //   -- partition temporaries overlap y (dead before first gemm writes y):
    //   pairs     [NE u32]        @ 7200016
    //   hist      [NB*NBLK i32]   @ 13600016
    //   btotal    [NB i32]        @ 14213104
    //   bucketoff [NB+1 i32]      @ 14216232
    char* ws = (char*)d_ws;
    float*          dinv      = (float*)(ws + 0);
    int*            rowstart  = (int*)(ws + 400000);
    int*            srcidx    = (int*)(ws + 800016);
    unsigned short* y         = (unsigned short*)(ws + 7200016);
    int*            gstart    = (int*)(ws + 20000016);
    unsigned*       pairs     = (unsigned*)(ws + 7200016);
    int*            hist      = (int*)(ws + 13600016);
    int*            btotal    = (int*)(ws + 14213104);
    int*            bucketoff = (int*)(ws + 14216232);

    // ---- edge partition + per-bucket counting sort (amortized across 3 layers) ----
    hist_buckets<<<NBLK, 256, 0, stream>>>(dst, hist);
    bucket_total<<<(NB + 3) / 4, 256, 0, stream>>>(hist, btotal);
    scan_totals<<<1, 1024, 0, stream>>>(btotal, bucketoff);
    scan_hist<<<(NB + 3) / 4, 256, 0, stream>>>(hist, bucketoff);
    bin_edges<<<NBLK, 256, 0, stream>>>(src, dst, hist, pairs);
    sort_bucket<<<NB, 256, 0, stream>>>(bucketoff, pairs, rowstart, srcidx, dinv);
    graph_bounds<<<(NN + 255) / 256, 256, 0, stream>>>(bat, gstart);

    const int gemmGrid = (NN + 63) / 64;
    const int aggrGrid = (NN + 8 * NPN - 1) / (8 * NPN);   // 8 half-waves/block, NPN nodes each

    gemm_mfma<<<gemmGrid, 256, 0, stream>>>(x, W1, dinv, y, NN);
    pull_aggr<<<aggrGrid, 256, 0, stream>>>(rowstart, srcidx, (const unsigned*)y, dinv, b1, h1);

    gemm_mfma<<<gemmGrid, 256, 0, stream>>>(h1, W2, dinv, y, NN);
    pull_aggr<<<aggrGrid, 256, 0, stream>>>(rowstart, srcidx, (const unsigned*)y, dinv, b2, h2);

    gemm_mfma<<<gemmGrid, 256, 0, stream>>>(h2, W3, dinv, y, NN);
    pull_aggr<<<aggrGrid, 256, 0, stream>>>(rowstart, srcidx, (const unsigned*)y, dinv, b3, h3);

    pool_ffn<<<NG, 256, 0, stream>>>(h3, gstart, Wf, bf, pooled, ffn, soft);
}